// Round 3
// baseline (198.262 us; speedup 1.0000x reference)
//
#include <hip/hip_runtime.h>

// LocallyConnectedLinear: out[b,h,w,o] = sum_k patch(x)[b,h,w,k] * W[h,w,k,o]
// k = c*9 + kh*3 + kw  (C slowest; verified passing in round 1)
// x[8,32,32,64] f32, W[30,30,576,64] f32, out[8,30,30,64] f32.
//
// Round 2 (resubmit — round 2 bench hit GPUAcquisitionTimeout, never ran):
// LDS removed from the hot loop.
//   lane  = output channel o (64 lanes = 64 C_out)
//   wave  = input-channel quarter (4 waves x 16 c x 9 taps = 144 k each)
// x operand is wave-uniform -> scalar s_load path (SGPR feeds v_fma directly).
// Weight loads: lane-contiguous global_load_dword, 256 B/segment, each weight
// read exactly once. Epilogue: 8 KB LDS 4-way cross-wave reduction.

#define HO 30
#define WO 30
#define HI 32
#define WI 32
#define CI 64
#define CO 64
#define BATCH 8
#define KTOT 576

__global__ __launch_bounds__(256) void lc_kernel(const float* __restrict__ x,
                                                 const float* __restrict__ wgt,
                                                 float* __restrict__ out) {
    const int hw = blockIdx.x;          // 0..899
    const int h  = hw / WO;
    const int w  = hw - h * WO;
    const int tid  = threadIdx.x;
    const int lane = tid & 63;                                  // output channel
    const int wv   = __builtin_amdgcn_readfirstlane(tid >> 6);  // wave id, uniform
    const int c0   = wv * 16;                                   // this wave's c-slice

    __shared__ float red[4 * BATCH * CO];  // 8 KB: [wave][b][o]

    float acc[BATCH];
    #pragma unroll
    for (int b = 0; b < BATCH; ++b) acc[b] = 0.f;

    // per-lane weight base for this location; k-offset applied as + k*64
    const float* wbase = wgt + (size_t)hw * (KTOT * CO) + lane;

    for (int p = 0; p < 9; ++p) {        // tap position: kh = p/3, kw = p%3
        const int kh = p / 3;
        const int kw = p - kh * 3;

        // 16 weight values for this (tap, c-slice): k = (c0+cc)*9 + p
        float wreg[16];
        #pragma unroll
        for (int cc = 0; cc < 16; ++cc)
            wreg[cc] = wbase[(size_t)(((c0 + cc) * 9 + p)) * CO];

        // x row for this tap: wave-uniform address -> scalar loads
        #pragma unroll
        for (int b = 0; b < BATCH; ++b) {
            const float* xb = x + (((b * HI + h + kh) * WI) + (w + kw)) * CI + c0;
            #pragma unroll
            for (int cc = 0; cc < 16; ++cc)
                acc[b] = fmaf(xb[cc], wreg[cc], acc[b]);
        }
    }

    // ---- cross-wave reduction (4 partials per (b,o)) --------------------
    #pragma unroll
    for (int b = 0; b < BATCH; ++b)
        red[(wv * BATCH + b) * CO + lane] = acc[b];
    __syncthreads();

    #pragma unroll
    for (int rep = 0; rep < 2; ++rep) {
        const int pidx = rep * 256 + tid;     // b*64 + o, 0..511
        const int b = pidx >> 6;
        const int o = pidx & 63;
        float s = red[pidx] + red[512 + pidx] + red[1024 + pidx] + red[1536 + pidx];
        out[(((size_t)b * HO + h) * WO + w) * CO + o] = s;
    }
}

extern "C" void kernel_launch(void* const* d_in, const int* in_sizes, int n_in,
                              void* d_out, int out_size, void* d_ws, size_t ws_size,
                              hipStream_t stream) {
    const float* x   = (const float*)d_in[0];
    const float* wgt = (const float*)d_in[1];
    float* out       = (float*)d_out;
    lc_kernel<<<dim3(HO * WO), dim3(256), 0, stream>>>(x, wgt, out);
}

// Round 4
// 196.789 us; speedup vs baseline: 1.0075x; 1.0075x over previous
//
#include <hip/hip_runtime.h>

// LocallyConnectedLinear: out[b,h,w,o] = sum_k patch(x)[b,h,w,k] * W[h,w,k,o]
// k = c*9 + kh*3 + kw  (C slowest; math verified rounds 1-3)
// x[8,32,32,64] f32, W[30,30,576,64] f32, out[8,30,30,64] f32.
//
// Round 4: round-2 structure + explicit software-pipelined weight prefetch.
//   lane = output channel o; wave = c-quarter (16 c x 9 taps = 144 k).
//   Per tap: 16 lane-contiguous global dword loads (256 B segments, each
//   weight read exactly once) double-buffered one tap ahead of the 256 FMAs;
//   x rows are wave-uniform -> scalar loads feeding v_fma.
// #pragma unroll 1 pins the rotating buffer (VGPR ~80, occupancy ample for
// the 14 waves/CU this 900-block grid provides).

#define HO 30
#define WO 30
#define HI 32
#define WI 32
#define CI 64
#define CO 64
#define BATCH 8
#define KTOT 576

__global__ __launch_bounds__(256) void lc_kernel(const float* __restrict__ x,
                                                 const float* __restrict__ wgt,
                                                 float* __restrict__ out) {
    const int hw = blockIdx.x;          // 0..899
    const int h  = hw / WO;
    const int w  = hw - h * WO;
    const int tid  = threadIdx.x;
    const int lane = tid & 63;                                  // output channel
    const int wv   = __builtin_amdgcn_readfirstlane(tid >> 6);  // wave id, uniform
    const int c0   = wv * 16;                                   // c-slice base

    __shared__ float red[4 * BATCH * CO];  // 8 KB: [wave][b][o]

    float acc[BATCH];
    #pragma unroll
    for (int b = 0; b < BATCH; ++b) acc[b] = 0.f;

    // per-lane weight base for this (location, c-slice); k=(c0+cc)*9+p
    // -> element offset from wbase = (cc*9 + p) * CO
    const float* wbase = wgt + (size_t)hw * (KTOT * CO) + (size_t)(c0 * 9) * CO + lane;

    // prologue: tap 0 weights
    float wcur[16];
    #pragma unroll
    for (int cc = 0; cc < 16; ++cc)
        wcur[cc] = wbase[(size_t)(cc * 9) * CO];

    #pragma unroll 1
    for (int p = 0; p < 9; ++p) {
        const int kh = p / 3;
        const int kw = p - kh * 3;

        // prefetch tap p+1 BEFORE consuming tap p (load-use distance ~1 tap)
        float wnxt[16];
        if (p < 8) {
            #pragma unroll
            for (int cc = 0; cc < 16; ++cc)
                wnxt[cc] = wbase[(size_t)(cc * 9 + p + 1) * CO];
        }

        // x rows: wave-uniform addresses -> scalar loads
        const float* xrow = x + ((h + kh) * WI + (w + kw)) * CI + c0;
        #pragma unroll
        for (int b = 0; b < BATCH; ++b) {
            const float* xb = xrow + b * (HI * WI * CI);
            #pragma unroll
            for (int cc = 0; cc < 16; ++cc)
                acc[b] = fmaf(xb[cc], wcur[cc], acc[b]);
        }

        if (p < 8) {
            #pragma unroll
            for (int cc = 0; cc < 16; ++cc) wcur[cc] = wnxt[cc];
        }
    }

    // ---- cross-wave reduction (4 partials per (b,o)) --------------------
    #pragma unroll
    for (int b = 0; b < BATCH; ++b)
        red[(wv * BATCH + b) * CO + lane] = acc[b];
    __syncthreads();

    #pragma unroll
    for (int rep = 0; rep < 2; ++rep) {
        const int pidx = rep * 256 + tid;     // b*64 + o, 0..511
        const int b = pidx >> 6;
        const int o = pidx & 63;
        float s = red[pidx] + red[512 + pidx] + red[1024 + pidx] + red[1536 + pidx];
        out[(((size_t)b * HO + h) * WO + w) * CO + o] = s;
    }
}

extern "C" void kernel_launch(void* const* d_in, const int* in_sizes, int n_in,
                              void* d_out, int out_size, void* d_ws, size_t ws_size,
                              hipStream_t stream) {
    const float* x   = (const float*)d_in[0];
    const float* wgt = (const float*)d_in[1];
    float* out       = (float*)d_out;
    lc_kernel<<<dim3(HO * WO), dim3(256), 0, stream>>>(x, wgt, out);
}